// Round 1
// 1144.708 us; speedup vs baseline: 4.6998x; 4.6998x over previous
//
#include <hip/hip_runtime.h>
#include <cmath>
#include <complex>
#include <algorithm>

#define N_NODES  32768
#define FEAT_DIM 480
#define TMUL     224
#define NB       4
#define ST       3328   // per-node LDS stride (floats)

// per-node LDS offsets (floats)
#define F0O 0
#define F1O 128
#define F2O 320
#define P0O 480
#define P1O 608
#define P2O 800
#define C0O 960
#define C1O 1184
#define C2O 2048
// Q (post-linear out) overlays C0/C1-head: written only after all C reads done
#define Q0O 960
#define Q1O 1088
#define Q2O 1280
// normgate scratch overlays C1/C2-head: only live while C is dead
#define INVO 1440
#define HO   1664
#define GO   1888
#define REDO 2112

__device__ __forceinline__ float siluf(float x){ return x * (1.0f/(1.0f + __expf(-x))); }

struct W3Pack { float v[363]; };

// ------------------------- host: exact Wigner-3j (mirrors reference) -------------------------
static double factd(int n){ double f=1.0; for(int i=2;i<=n;++i) f*=(double)i; return f; }

static double su2_cg(int j1,int j2,int j3,int m1,int m2,int m3){
  if (m1+m2 != m3) return 0.0;
  double pref = std::sqrt((2.0*j3+1.0)*factd(j3+j1-j2)*factd(j3-j1+j2)*factd(j1+j2-j3)/factd(j1+j2+j3+1));
  pref *= std::sqrt(factd(j3+m3)*factd(j3-m3)*factd(j1-m1)*factd(j1+m1)*factd(j2-m2)*factd(j2+m2));
  double s=0.0;
  int vmin = std::max(0, std::max(j2-j3-m1, j1-j3+m2));
  int vmax = std::min(j2+m2, std::min(j1-m1, j1+j2-j3));
  for (int v=vmin; v<=vmax; ++v){
    double d = factd(v)*factd(j1+j2-j3-v)*factd(j1-m1-v)*factd(j2+m2-v)*factd(j3-j2+m1+v)*factd(j3-j1-m2+v);
    s += ((v&1)? -1.0 : 1.0)/d;
  }
  return pref*s;
}

typedef std::complex<double> cd;

static void qmat(int l, cd* q){
  int d=2*l+1;
  for (int a=0;a<d*d;++a) q[a]=cd(0,0);
  double is2 = 1.0/std::sqrt(2.0);
  for (int m=-l; m<0; ++m){
    int am=-m;
    q[(l+m)*d + (l+am)] = cd(is2,0);
    q[(l+m)*d + (l-am)] = cd(0,-is2);
  }
  q[l*d+l] = cd(1,0);
  for (int m=1;m<=l;++m){
    double sg = (m&1)? -1.0:1.0;
    q[(l+m)*d + (l+m)] = cd(sg*is2,0);
    q[(l+m)*d + (l-m)] = cd(0,sg*is2);
  }
  cd f = (l==0)? cd(1,0) : (l==1? cd(0,-1) : cd(-1,0)); // (-i)^l for l<=2
  for (int a=0;a<d*d;++a) q[a]*=f;
}

static void wigner3j(int l1,int l2,int l3, float* out){
  int d1=2*l1+1,d2=2*l2+1,d3=2*l3+1;
  double Cc[5][5][5] = {};
  for (int m1=-l1;m1<=l1;++m1) for (int m2=-l2;m2<=l2;++m2){
    int m3=m1+m2;
    if (m3>=-l3 && m3<=l3) Cc[l1+m1][l2+m2][l3+m3] = su2_cg(l1,l2,l3,m1,m2,m3);
  }
  cd q1[25],q2[25],q3[25];
  qmat(l1,q1); qmat(l2,q2); qmat(l3,q3);
  double re[125], im[125];
  double nr=0, ni=0;
  for (int i=0;i<d1;++i) for (int j=0;j<d2;++j) for (int k=0;k<d3;++k){
    cd s(0,0);
    for (int a=0;a<d1;++a) for (int b=0;b<d2;++b) for (int c=0;c<d3;++c){
      double cc = Cc[a][b][c];
      if (cc != 0.0) s += q1[a*d1+i]*q2[b*d2+j]*std::conj(q3[c*d3+k])*cc;
    }
    int o=(i*d2+j)*d3+k;
    re[o]=s.real(); im[o]=s.imag();
    nr += s.real()*s.real(); ni += s.imag()*s.imag();
  }
  bool useRe = std::sqrt(nr) >= std::sqrt(ni);
  double nrm = std::sqrt(useRe? nr : ni);
  for (int o=0;o<d1*d2*d3;++o) out[o] = (float)((useRe? re[o] : im[o]) / nrm);
}

static W3Pack build_w3(){
  W3Pack W;
  wigner3j(0,0,0, W.v+0);
  wigner3j(0,1,1, W.v+1);
  wigner3j(0,2,2, W.v+10);
  wigner3j(1,0,1, W.v+35);
  wigner3j(1,1,0, W.v+44);
  wigner3j(1,1,2, W.v+53);
  wigner3j(1,2,1, W.v+98);
  wigner3j(2,0,2, W.v+143);
  wigner3j(2,1,1, W.v+168);
  wigner3j(2,2,0, W.v+213);
  wigner3j(2,2,2, W.v+238);
  return W;
}

// ------------------------- device: tpw regroup (column-major, scale folded) -------------------------
// Group A (i2=0, M2=128, NJ=1): rows: p1 u(128) | p4 u(64) | p8 u(32)  -> wt[v*224 + r], v<128
// Group B (i2=1, M2=64,  NJ=3): rows: p2(128) | p5(64) | p6(64) | p9(32) -> wt[28672 + v*288 + r], v<64
// Group C (i2=2, M2=32,  NJ=5): rows: p3(128) | p7(64) | p10(32) | p11(32) -> wt[47104 + v*256 + r], v<32
__global__ __launch_bounds__(256) void prep_tpw(const float* __restrict__ tpw, float* __restrict__ wt)
{
  const int t = blockIdx.x*256 + threadIdx.x;
  if (t >= 55296) return;
  float v;
  if (t < 28672) {
    const int vv = t / 224, r = t - vv*224;
    int off, u;
    if (r < 128)      { off = 0;     u = r; }
    else if (r < 192) { off = 28672; u = r-128; }
    else              { off = 47104; u = r-192; }
    v = tpw[off + u*128 + vv] * 0.08838834764831845f;   // 1/sqrt(128)
  } else if (t < 47104) {
    const int t2 = t-28672; const int vv = t2/288, r = t2 - vv*288;
    int off, u;
    if (r < 128)      { off = 16384; u = r; }
    else if (r < 192) { off = 36864; u = r-128; }
    else if (r < 256) { off = 40960; u = r-192; }
    else              { off = 51200; u = r-256; }
    v = tpw[off + u*64 + vv] * 0.125f;                   // 1/sqrt(64)
  } else {
    const int t3 = t-47104; const int vv = t3/256, r = t3 & 255;
    int off, u;
    if (r < 128)      { off = 24576; u = r; }
    else if (r < 192) { off = 45056; u = r-128; }
    else if (r < 224) { off = 53248; u = r-192; }
    else              { off = 54272; u = r-224; }
    v = tpw[off + u*32 + vv] * 0.17677669529663687f;     // 1/sqrt(32)
  }
  wt[t] = v;
}

// ------------------------- generic column matvec over NB nodes -------------------------
template<int N>
__device__ __forceinline__ void matcolr(const float* __restrict__ Wg, const int wstride, const int col,
                                        const float* __restrict__ Lp, const int inbase, float (&acc)[NB])
{
  #pragma unroll
  for (int nb=0;nb<NB;++nb) acc[nb]=0.f;
  const float* wp = Wg + col;
  #pragma unroll 2
  for (int u=0; u<N; u+=4) {
    const float wA = wp[(u+0)*wstride];
    const float wB = wp[(u+1)*wstride];
    const float wC = wp[(u+2)*wstride];
    const float wD = wp[(u+3)*wstride];
    #pragma unroll
    for (int nb=0;nb<NB;++nb) {
      const float4 x = *reinterpret_cast<const float4*>(&Lp[nb*ST + inbase + u]);
      acc[nb] += x.x*wA + x.y*wB + x.z*wC + x.w*wD;
    }
  }
}

// ------------------------- normgate (inv -> wave-parallel mean/var -> MLP -> G) -------------------------
__device__ __forceinline__ void normgate(float* __restrict__ L, const int c,
                                         const int B0, const int B1, const int B2,
                                         const float* __restrict__ gw1, const float* __restrict__ gb1,
                                         const float* __restrict__ gw2, const float* __restrict__ gb2)
{
  if (c < 128) {
    #pragma unroll
    for (int nb=0;nb<NB;++nb) L[nb*ST+INVO+c] = L[nb*ST+B0+c];
  } else if (c < 192) {
    const int v = c-128;
    #pragma unroll
    for (int nb=0;nb<NB;++nb) {
      float s = 1e-12f;
      #pragma unroll
      for (int i=0;i<3;++i){ const float x = L[nb*ST+B1+i*64+v]; s += x*x; }
      L[nb*ST+INVO+c] = sqrtf(s);
    }
  } else if (c < 224) {
    const int v = c-192;
    #pragma unroll
    for (int nb=0;nb<NB;++nb) {
      float s = 1e-12f;
      #pragma unroll
      for (int i=0;i<5;++i){ const float x = L[nb*ST+B2+i*32+v]; s += x*x; }
      L[nb*ST+INVO+c] = sqrtf(s);
    }
  }
  __syncthreads();
  {
    const int w = c>>6, l = c&63;   // wave w <-> node w
    float s=0.f, s2=0.f, x;
    x = L[w*ST+INVO+l];     s+=x; s2+=x*x;
    x = L[w*ST+INVO+64+l];  s+=x; s2+=x*x;
    x = L[w*ST+INVO+128+l]; s+=x; s2+=x*x;
    if (l < 32) { x = L[w*ST+INVO+192+l]; s+=x; s2+=x*x; }
    #pragma unroll
    for (int off=32; off>=1; off>>=1) {
      s  += __shfl_xor(s,  off, 64);
      s2 += __shfl_xor(s2, off, 64);
    }
    if (l==0) {
      const float m = s*(1.f/224.f);
      L[w*ST+REDO+0] = m;
      L[w*ST+REDO+1] = rsqrtf(s2*(1.f/224.f) - m*m + 1e-5f);
    }
  }
  __syncthreads();
  if (c < TMUL) {
    #pragma unroll
    for (int nb=0;nb<NB;++nb)
      L[nb*ST+INVO+c] = (L[nb*ST+INVO+c]-L[nb*ST+REDO+0])*L[nb*ST+REDO+1];
  }
  __syncthreads();
  if (c < TMUL) {
    float acc[NB];
    matcolr<224>(gw1, 224, c, L, INVO, acc);
    const float b = gb1[c];
    #pragma unroll
    for (int nb=0;nb<NB;++nb) L[nb*ST+HO+c] = siluf(acc[nb]+b);
  }
  __syncthreads();
  if (c < TMUL) {
    float acc[NB];
    matcolr<224>(gw2, 224, c, L, HO, acc);
    const float b = gb2[c];
    #pragma unroll
    for (int nb=0;nb<NB;++nb) L[nb*ST+GO+c] = siluf(acc[nb]+b);
  }
  // no trailing sync: thread c's G[*][c] is self-written; callers sync before cross-thread G reads
}

// ------------------------- CG rows, groups B and C (t in regs, fused y) -------------------------
__device__ __forceinline__ void cg_rowB(const int r, const float* __restrict__ wt,
                                        const W3Pack& W, float* __restrict__ L)
{
  float tb[3][NB];
  #pragma unroll
  for (int j=0;j<3;++j)
    #pragma unroll
    for (int nb=0;nb<NB;++nb) tb[j][nb]=0.f;
  const float* wp = wt + 28672 + r;
  #pragma unroll 2
  for (int v=0; v<64; v+=4) {
    const float wA=wp[(v+0)*288], wB=wp[(v+1)*288], wC=wp[(v+2)*288], wD=wp[(v+3)*288];
    #pragma unroll
    for (int j=0;j<3;++j) {
      #pragma unroll
      for (int nb=0;nb<NB;++nb) {
        const float4 x = *reinterpret_cast<const float4*>(&L[nb*ST+P1O+j*64+v]);
        tb[j][nb] += x.x*wA + x.y*wB + x.z*wC + x.w*wD;
      }
    }
  }
  if (r < 128) {                       // p2 (0,1,1): out C1 row r
    #pragma unroll
    for (int nb=0;nb<NB;++nb) {
      const float f = L[nb*ST+F0O+r];
      #pragma unroll
      for (int k=0;k<3;++k) {
        float s=0.f;
        #pragma unroll
        for (int j=0;j<3;++j) s += tb[j][nb]*W.v[1+j*3+k];
        L[nb*ST+C1O+k*288+r] = f*s;
      }
    }
  } else if (r < 192) {                // p5 (1,1,0): out C0 row 128+u
    const int u=r-128;
    #pragma unroll
    for (int nb=0;nb<NB;++nb) {
      float y=0.f;
      #pragma unroll
      for (int i=0;i<3;++i) {
        float s=0.f;
        #pragma unroll
        for (int j=0;j<3;++j) s += tb[j][nb]*W.v[44+i*3+j];
        y += L[nb*ST+F1O+i*64+u]*s;
      }
      L[nb*ST+C0O+128+u] = y;
    }
  } else if (r < 256) {                // p6 (1,1,2): out C2 row 128+u
    const int u=r-192;
    #pragma unroll
    for (int nb=0;nb<NB;++nb) {
      float f[3];
      #pragma unroll
      for (int i=0;i<3;++i) f[i]=L[nb*ST+F1O+i*64+u];
      #pragma unroll
      for (int k=0;k<5;++k) {
        float y=0.f;
        #pragma unroll
        for (int i=0;i<3;++i) {
          float s=0.f;
          #pragma unroll
          for (int j=0;j<3;++j) s += tb[j][nb]*W.v[53+(i*3+j)*5+k];
          y += f[i]*s;
        }
        L[nb*ST+C2O+k*256+128+u] = y;
      }
    }
  } else {                             // p9 (2,1,1): out C1 row 256+u
    const int u=r-256;
    #pragma unroll
    for (int nb=0;nb<NB;++nb) {
      float f[5];
      #pragma unroll
      for (int i=0;i<5;++i) f[i]=L[nb*ST+F2O+i*32+u];
      #pragma unroll
      for (int k=0;k<3;++k) {
        float y=0.f;
        #pragma unroll
        for (int i=0;i<5;++i) {
          float s=0.f;
          #pragma unroll
          for (int j=0;j<3;++j) s += tb[j][nb]*W.v[168+(i*3+j)*3+k];
          y += f[i]*s;
        }
        L[nb*ST+C1O+k*288+256+u] = y;
      }
    }
  }
}

__device__ __forceinline__ void cg_rowC(const int r, const float* __restrict__ wt,
                                        const W3Pack& W, float* __restrict__ L)
{
  float tc[5][NB];
  #pragma unroll
  for (int j=0;j<5;++j)
    #pragma unroll
    for (int nb=0;nb<NB;++nb) tc[j][nb]=0.f;
  const float* wp = wt + 47104 + r;
  #pragma unroll 2
  for (int v=0; v<32; v+=4) {
    const float wA=wp[(v+0)*256], wB=wp[(v+1)*256], wC=wp[(v+2)*256], wD=wp[(v+3)*256];
    #pragma unroll
    for (int j=0;j<5;++j) {
      #pragma unroll
      for (int nb=0;nb<NB;++nb) {
        const float4 x = *reinterpret_cast<const float4*>(&L[nb*ST+P2O+j*32+v]);
        tc[j][nb] += x.x*wA + x.y*wB + x.z*wC + x.w*wD;
      }
    }
  }
  if (r < 128) {                       // p3 (0,2,2): out C2 row r
    #pragma unroll
    for (int nb=0;nb<NB;++nb) {
      const float f = L[nb*ST+F0O+r];
      #pragma unroll
      for (int k=0;k<5;++k) {
        float s=0.f;
        #pragma unroll
        for (int j=0;j<5;++j) s += tc[j][nb]*W.v[10+j*5+k];
        L[nb*ST+C2O+k*256+r] = f*s;
      }
    }
  } else if (r < 192) {                // p7 (1,2,1): out C1 row 192+u
    const int u=r-128;
    #pragma unroll
    for (int nb=0;nb<NB;++nb) {
      float f[3];
      #pragma unroll
      for (int i=0;i<3;++i) f[i]=L[nb*ST+F1O+i*64+u];
      #pragma unroll
      for (int k=0;k<3;++k) {
        float y=0.f;
        #pragma unroll
        for (int i=0;i<3;++i) {
          float s=0.f;
          #pragma unroll
          for (int j=0;j<5;++j) s += tc[j][nb]*W.v[98+(i*5+j)*3+k];
          y += f[i]*s;
        }
        L[nb*ST+C1O+k*288+192+u] = y;
      }
    }
  } else if (r < 224) {                // p10 (2,2,0): out C0 row 192+u
    const int u=r-192;
    #pragma unroll
    for (int nb=0;nb<NB;++nb) {
      float y=0.f;
      #pragma unroll
      for (int i=0;i<5;++i) {
        float s=0.f;
        #pragma unroll
        for (int j=0;j<5;++j) s += tc[j][nb]*W.v[213+i*5+j];
        y += L[nb*ST+F2O+i*32+u]*s;
      }
      L[nb*ST+C0O+192+u] = y;
    }
  } else {                             // p11 (2,2,2): out C2 row 224+u
    const int u=r-224;
    #pragma unroll
    for (int nb=0;nb<NB;++nb) {
      float f[5];
      #pragma unroll
      for (int i=0;i<5;++i) f[i]=L[nb*ST+F2O+i*32+u];
      #pragma unroll
      for (int k=0;k<5;++k) {
        float y=0.f;
        #pragma unroll
        for (int i=0;i<5;++i) {
          float s=0.f;
          #pragma unroll
          for (int j=0;j<5;++j) s += tc[j][nb]*W.v[238+(i*5+j)*5+k];
          y += f[i]*s;
        }
        L[nb*ST+C2O+k*256+224+u] = y;
      }
    }
  }
}

// ------------------------- fused kernel: NB nodes per block -------------------------
__global__ __launch_bounds__(256, 2) void fused4(
  const float* __restrict__ feat,
  const float* __restrict__ w0, const float* __restrict__ w1, const float* __restrict__ w2,
  const float* __restrict__ pgw1, const float* __restrict__ pgb1,
  const float* __restrict__ pgw2, const float* __restrict__ pgb2,
  const float* __restrict__ wt,
  const float* __restrict__ pw0, const float* __restrict__ pw1, const float* __restrict__ pw2,
  const float* __restrict__ qgw1, const float* __restrict__ qgb1,
  const float* __restrict__ qgw2, const float* __restrict__ qgb2,
  float* __restrict__ outp, const W3Pack W)
{
  __shared__ float L[ST*NB];
  const int c = threadIdx.x;
  const size_t gbase = (size_t)blockIdx.x * (FEAT_DIM*NB);

  // ---- load + de-interleave (component-major F blocks) ----
  for (int t=c; t<FEAT_DIM*NB; t+=256) {
    const float val = feat[gbase + t];
    const int nb = t / FEAT_DIM;
    const int ch = t - nb*FEAT_DIM;
    int loc;
    if (ch < 128) loc = F0O + ch;
    else if (ch < 320) { const int q = ch-128; const int u = q/3; loc = F1O + (q-u*3)*64 + u; }
    else               { const int q = ch-320; const int u = q/5; loc = F2O + (q-u*5)*32 + u; }
    L[nb*ST + loc] = val;
  }
  __syncthreads();

  // ---- pre-linear (slot-balanced: every thread ~<=192 MAC/node) ----
  {
    float a1[NB], a2[NB];
    int o1, o2=-1; float s1, s2s=0.f;
    if (c < 128) { matcolr<128>(w0, 128, c, L, F0O, a1); o1 = P0O+c; s1 = 0.08838834764831845f; }
    else { const int q=c-128; const int i=q>>6, v=q&63;
           matcolr<64>(w1, 64, v, L, F1O+i*64, a1); o1 = P1O+i*64+v; s1 = 0.125f; }
    if (c < 64) { matcolr<64>(w1, 64, c, L, F1O+128, a2); o2 = P1O+128+c; s2s = 0.125f; }
    else if (c < 224) { const int q=c-64; const int i=q>>5, v=q&31;
           matcolr<32>(w2, 32, v, L, F2O+i*32, a2); o2 = P2O+i*32+v; s2s = 0.17677669529663687f; }
    #pragma unroll
    for (int nb=0;nb<NB;++nb) L[nb*ST + o1] = a1[nb]*s1;
    if (o2 >= 0) {
      #pragma unroll
      for (int nb=0;nb<NB;++nb) L[nb*ST + o2] = a2[nb]*s2s;
    }
  }
  __syncthreads();

  // ---- pre normgate + gate P in place ----
  normgate(L, c, P0O, P1O, P2O, pgw1, pgb1, pgw2, pgb2);
  if (c < 128) {
    #pragma unroll
    for (int nb=0;nb<NB;++nb) L[nb*ST+P0O+c] *= L[nb*ST+GO+c];
  } else if (c < 192) {
    const int v=c-128;
    #pragma unroll
    for (int nb=0;nb<NB;++nb) { const float g=L[nb*ST+GO+c];
      #pragma unroll
      for (int i=0;i<3;++i) L[nb*ST+P1O+i*64+v] *= g; }
  } else if (c < 224) {
    const int v=c-192;
    #pragma unroll
    for (int nb=0;nb<NB;++nb) { const float g=L[nb*ST+GO+c];
      #pragma unroll
      for (int i=0;i<5;++i) L[nb*ST+P2O+i*32+v] *= g; }
  }
  __syncthreads();   // P gated; also guarantees all MLP2 H-reads done before CG overwrites C1/H region

  // ---- CG coupling: group A (thread=row, t in reg, fused y) ----
  if (c < 224) {
    float tA[NB];
    #pragma unroll
    for (int nb=0;nb<NB;++nb) tA[nb]=0.f;
    const float* wp = wt + c;
    #pragma unroll 2
    for (int v=0; v<128; v+=4) {
      const float wA=wp[(v+0)*224], wB=wp[(v+1)*224], wC=wp[(v+2)*224], wD=wp[(v+3)*224];
      #pragma unroll
      for (int nb=0;nb<NB;++nb) {
        const float4 x = *reinterpret_cast<const float4*>(&L[nb*ST+P0O+v]);
        tA[nb] += x.x*wA + x.y*wB + x.z*wC + x.w*wD;
      }
    }
    if (c < 128) {                     // p1 (0,0,0): out C0 row c
      #pragma unroll
      for (int nb=0;nb<NB;++nb) L[nb*ST+C0O+c] = L[nb*ST+F0O+c]*tA[nb]*W.v[0];
    } else if (c < 192) {              // p4 (1,0,1): out C1 row 128+u
      const int u=c-128;
      #pragma unroll
      for (int nb=0;nb<NB;++nb) {
        const float f0=L[nb*ST+F1O+u], f1=L[nb*ST+F1O+64+u], f2=L[nb*ST+F1O+128+u];
        #pragma unroll
        for (int k=0;k<3;++k)
          L[nb*ST+C1O+k*288+128+u] = tA[nb]*(f0*W.v[35+k] + f1*W.v[38+k] + f2*W.v[41+k]);
      }
    } else {                           // p8 (2,0,2): out C2 row 192+u
      const int u=c-192;
      #pragma unroll
      for (int nb=0;nb<NB;++nb) {
        float f[5];
        #pragma unroll
        for (int i=0;i<5;++i) f[i]=L[nb*ST+F2O+i*32+u];
        #pragma unroll
        for (int k=0;k<5;++k) {
          float y=0.f;
          #pragma unroll
          for (int i=0;i<5;++i) y += f[i]*W.v[143+i*5+k];
          L[nb*ST+C2O+k*256+192+u] = tA[nb]*y;
        }
      }
    }
  }
  // groups B (288 rows) and C (256 rows)
  cg_rowB(c, wt, W, L);
  if (c >= 224) cg_rowB(c+32, wt, W, L);
  cg_rowC(c, wt, W, L);
  __syncthreads();

  // ---- post-linear (reg-staged: Q overlays C head, write after all C reads) ----
  {
    float pa[NB], pb[NB];
    int po1, po2=-1; float ps1, ps2=0.f;
    if (c < 128) { matcolr<224>(pw0, 128, c, L, C0O, pa); po1 = Q0O+c; ps1 = 0.06681531047810609f; }
    else { const int q=c-128; const int i=q>>6, v=q&63;
           matcolr<288>(pw1, 64, v, L, C1O+i*288, pa); po1 = Q1O+i*64+v; ps1 = 0.05892556509887896f; }
    if (c < 64) { matcolr<288>(pw1, 64, c, L, C1O+2*288, pb); po2 = Q1O+128+c; ps2 = 0.05892556509887896f; }
    else if (c < 224) { const int q=c-64; const int i=q>>5, v=q&31;
           matcolr<256>(pw2, 32, v, L, C2O+i*256, pb); po2 = Q2O+i*32+v; ps2 = 0.0625f; }
    __syncthreads();   // all C reads complete before Q overwrite
    #pragma unroll
    for (int nb=0;nb<NB;++nb) L[nb*ST+po1] = pa[nb]*ps1;
    if (po2 >= 0) {
      #pragma unroll
      for (int nb=0;nb<NB;++nb) L[nb*ST+po2] = pb[nb]*ps2;
    }
  }
  __syncthreads();

  // ---- post normgate ----
  normgate(L, c, Q0O, Q1O, Q2O, qgw1, qgb1, qgw2, qgb2);
  __syncthreads();   // final reads G cross-thread

  // ---- final: out = feat + pre_gated + post*G (re-interleave, coalesced store) ----
  for (int t=c; t<FEAT_DIM*NB; t+=256) {
    const int nb = t / FEAT_DIM;
    const int ch = t - nb*FEAT_DIM;
    const float* Lb = L + nb*ST;
    float val;
    if (ch < 128) {
      val = Lb[F0O+ch] + Lb[P0O+ch] + Lb[Q0O+ch]*Lb[GO+ch];
    } else if (ch < 320) {
      const int q=ch-128; const int u=q/3; const int o=(q-u*3)*64+u;
      val = Lb[F1O+o] + Lb[P1O+o] + Lb[Q1O+o]*Lb[GO+128+u];
    } else {
      const int q=ch-320; const int u=q/5; const int o=(q-u*5)*32+u;
      val = Lb[F2O+o] + Lb[P2O+o] + Lb[Q2O+o]*Lb[GO+192+u];
    }
    outp[gbase + t] = val;
  }
}

// ------------------------- launch -------------------------
extern "C" void kernel_launch(void* const* d_in, const int* in_sizes, int n_in,
                              void* d_out, int out_size, void* d_ws, size_t ws_size,
                              hipStream_t stream)
{
  (void)in_sizes; (void)n_in; (void)out_size; (void)ws_size;
  const float* feat  = (const float*)d_in[0];
  const float* prw0  = (const float*)d_in[1];
  const float* prw1  = (const float*)d_in[2];
  const float* prw2  = (const float*)d_in[3];
  const float* pngw1 = (const float*)d_in[4];
  const float* pngb1 = (const float*)d_in[5];
  const float* pngw2 = (const float*)d_in[6];
  const float* pngb2 = (const float*)d_in[7];
  const float* tpw   = (const float*)d_in[8];
  const float* pow0  = (const float*)d_in[9];
  const float* pow1  = (const float*)d_in[10];
  const float* pow2  = (const float*)d_in[11];
  const float* qngw1 = (const float*)d_in[12];
  const float* qngb1 = (const float*)d_in[13];
  const float* qngw2 = (const float*)d_in[14];
  const float* qngb2 = (const float*)d_in[15];

  float* wt = (float*)d_ws;            // 55296 floats: regrouped tpw

  W3Pack W = build_w3();               // host-only, identical every call

  prep_tpw<<<dim3(216), dim3(256), 0, stream>>>(tpw, wt);

  fused4<<<dim3(N_NODES/NB), dim3(256), 0, stream>>>(
      feat, prw0, prw1, prw2, pngw1, pngb1, pngw2, pngb2,
      wt, pow0, pow1, pow2, qngw1, qngb1, qngw2, qngb2,
      (float*)d_out, W);
}